// Round 1
// baseline (288.148 us; speedup 1.0000x reference)
//
#include <hip/hip_runtime.h>
#include <math.h>

typedef unsigned int uint;
typedef unsigned short ushort;
typedef unsigned long long u64;
typedef __attribute__((ext_vector_type(8))) short short8;
typedef __attribute__((ext_vector_type(4))) float f32x4;

// Problem: z (16,256,32,32) fp32, emb (8192,256) fp32. N=16384 rows, K=256, C=8192 codes.
// out (fp32): [0,4194304) z_q (b,c,h,w) | [4194304] loss | [4194305,+16384) idx as float
//
// Pipeline: bf16-MFMA screen (codebook 64-code/32KB panel LDS-resident, barrier-free
// K-loop, 3 blocks/CU) -> per-row per-8code-group max, 2 groups packed bf16 in u32
// (gmax[n][512]) -> wave-per-row select within margin of global max -> exact fp32
// rescore (d = fl32((sumz + sume) - 2*dot), matching the reference expression shape,
// sume folded into the dot loop) -> u64 (score|idx) min, lowest-index ties.
//
// HW lesson (round 9): __launch_bounds__ 2nd arg acted as CUDA min-BLOCKS/CU here
// ((512,4) -> 64 VGPR -> acc spilled -> 525MB scratch FETCH). Never cap below live set.
// HW lesson (round 10): post-timing idx divergence across graph replays traced to the
// only order-dependent primitive in the pipeline: LDS atomicAdd hit compaction in
// select_rescore. Replaced with ballot+popc prefix compaction (deterministic slots,
// no LDS atomics). Also added the +||e||^2 term so near-tie rounding tracks reference.
//
// ws: zt fp32[16384][256] @0 | zpk 8MB | epk 4MB | sumz | gmax u32[16384][512] | best | loss,ctr
#define WS_ZT   0ull
#define WS_ZPK  16777216ull
#define WS_EPK  25165824ull
#define WS_SUMZ 29360128ull
#define WS_GMAX 29425664ull
#define WS_BEST 62980096ull
#define WS_LOSS 63111168ull

#define DOT_MARGIN 1.5e-4f  // r9 bound: 2*eps_screen + bf16 store ulp ~4.1e-5; >3.5x safety

__device__ __forceinline__ ushort f2bf(float f) {           // RNE fp32->bf16
  uint b = __float_as_uint(f);
  b += 0x7fffu + ((b >> 16) & 1u);
  return (ushort)(b >> 16);
}
__device__ __forceinline__ uint ford(float f) {             // orderable uint
  uint b = __float_as_uint(f);
  return (b & 0x80000000u) ? ~b : (b | 0x80000000u);
}
__device__ __forceinline__ void gload_lds16(const void* g, void* l) {
  __builtin_amdgcn_global_load_lds(
      (const __attribute__((address_space(1))) unsigned int*)g,
      (__attribute__((address_space(3))) unsigned int*)l, 16, 0, 0);
}

// ---------------- prep: zt[n][k] fp32 + zpk fragment-packed bf16 (validated)
__global__ __launch_bounds__(256) void prep_z(const float* __restrict__ z,
                                              float* __restrict__ zt,
                                              ushort* __restrict__ zpk) {
  __shared__ float tile[64][65];
  const int bid = blockIdx.x;
  const int kt = bid & 3, hwt = (bid >> 2) & 15, b = bid >> 6;
  const int t = threadIdx.x, lane = t & 63, grp = t >> 6;
  const float* src = z + b * 262144 + (kt * 64) * 1024 + hwt * 64;
  for (int kk = grp; kk < 64; kk += 4)
    tile[kk][lane] = src[kk * 1024 + lane];                 // coalesced over hw
  __syncthreads();
  for (int rr = grp; rr < 64; rr += 4) {                    // zt: coalesced over k
    const int n = b * 1024 + hwt * 64 + rr;
    zt[n * 256 + kt * 64 + lane] = tile[lane][rr];
  }
  for (int u = t; u < 512; u += 256) {                      // zpk: 16B frag pieces
    const int n_loc = u & 63, kg = u >> 6;
    const int n = b * 1024 + hwt * 64 + n_loc;
    const int k0 = kt * 64 + kg * 8;
    short8 s;
#pragma unroll
    for (int j = 0; j < 8; ++j) s[j] = (short)f2bf(tile[kg * 8 + j][n_loc]);
    *(short8*)(zpk + (size_t)(n >> 4) * 4096 + (k0 >> 5) * 512 +
               ((k0 >> 3) & 3) * 128 + (n & 15) * 8) = s;
  }
}

// ---------------- prep: epk fragment-packed bf16 codebook (validated)
__global__ __launch_bounds__(256) void prep_e(const float* __restrict__ emb,
                                              ushort* __restrict__ epk) {
  const int u = blockIdx.x * 256 + threadIdx.x;             // 262144 threads
  const int c = u >> 5, k0 = (u & 31) * 8;
  const float4 v0 = *(const float4*)(emb + c * 256 + k0);
  const float4 v1 = *(const float4*)(emb + c * 256 + k0 + 4);
  short8 s;
  s[0] = (short)f2bf(v0.x); s[1] = (short)f2bf(v0.y);
  s[2] = (short)f2bf(v0.z); s[3] = (short)f2bf(v0.w);
  s[4] = (short)f2bf(v1.x); s[5] = (short)f2bf(v1.y);
  s[6] = (short)f2bf(v1.z); s[7] = (short)f2bf(v1.w);
  *(short8*)(epk + (size_t)(c >> 4) * 4096 + (k0 >> 5) * 512 +
             ((k0 >> 3) & 3) * 128 + (c & 15) * 8) = s;
}

// ---------------- sumz[n] = ||z_n||^2, sequential-k fp32 (validated numerics)
__global__ __launch_bounds__(256) void zsum_kernel(const float* __restrict__ z,
                                                   float* __restrict__ sumz) {
  const int n = (blockIdx.x << 8) + threadIdx.x;
  const int b = n >> 10, hw = n & 1023;
  const float* zb = z + b * 262144 + hw;
  float s = 0.f;
#pragma unroll 8
  for (int c = 0; c < 256; ++c) { const float v = zb[c << 10]; s += v * v; }
  sumz[n] = s;
}

// ---------------- screening GEMM: 64-code (32 KB) panel LDS-resident, barrier-free
// 256 threads / 4 waves; all waves share the 4 code-tiles, wave w owns row-quarter w.
// Block: 1024 rows x 64 codes, 4 strips of 256 rows; per wave-strip 64 rows x 64 codes.
// grid 2048 = 8 XCD x 16 colb x 16 rowg; VGPR ~140 -> 3 blocks/CU = 12 waves/CU.
__global__ __launch_bounds__(256) void gemm_screen(const ushort* __restrict__ zpk,
                                                   const ushort* __restrict__ epk,
                                                   uint* __restrict__ gmax) {
  __shared__ ushort Cs[16384];   // 32 KB: 32 frags x 1KB, frag f = c16loc*8 + k32
  const int t = threadIdx.x;
  const int w = t >> 6, lane = t & 63;
  const int bid = blockIdx.x;
  const int x = bid & 7, y = bid >> 3;
  const int colb = (y & 15) * 8 + x;       // 0..127; XCD x owns 16 panels (512KB, L2)
  const int rowg = y >> 4;                 // 0..15
  const int n0 = rowg << 10;
  const int m16 = lane & 15, q = lane >> 4;

  // stage code panel once: 8 coalesced 1KB DMAs per wave
#pragma unroll
  for (int f2 = 0; f2 < 8; ++f2) {
    const int f = w * 8 + f2;
    gload_lds16(epk + (size_t)colb * 16384 + f * 512 + lane * 8, (char*)Cs + f * 1024);
  }
  __syncthreads();                         // only barrier in the kernel

  short8 zc[4], zn[4];                     // z frags, k32-granular rotation
  const ushort* zb0 = zpk + ((size_t)(n0 >> 4) + w * 4) * 4096 + lane * 8;
#pragma unroll
  for (int jr = 0; jr < 4; ++jr) zc[jr] = *(const short8*)(zb0 + jr * 4096);

  for (int strip = 0; strip < 4; ++strip) {
    const int rbase = n0 + strip * 256 + w * 64;
    const ushort* zb = zpk + (size_t)(rbase >> 4) * 4096 + lane * 8;
    f32x4 acc[4][4];                       // [ic][jr]
#pragma unroll
    for (int i = 0; i < 4; ++i)
#pragma unroll
      for (int j = 0; j < 4; ++j) acc[i][j] = {0.f, 0.f, 0.f, 0.f};

#pragma unroll
    for (int s32 = 0; s32 < 8; ++s32) {    // k32 steps over K=256
      if (s32 < 7) {
#pragma unroll
        for (int jr = 0; jr < 4; ++jr)
          zn[jr] = *(const short8*)(zb + jr * 4096 + (s32 + 1) * 512);
      }
      short8 cv[4];
#pragma unroll
      for (int ic = 0; ic < 4; ++ic)
        cv[ic] = *(const short8*)&Cs[(size_t)(ic * 8 + s32) * 512 + lane * 8];
#pragma unroll
      for (int ic = 0; ic < 4; ++ic)
#pragma unroll
        for (int jr = 0; jr < 4; ++jr)
          acc[ic][jr] = __builtin_amdgcn_mfma_f32_16x16x32_bf16(cv[ic], zc[jr],
                                                                acc[ic][jr], 0, 0, 0);
#pragma unroll
      for (int jr = 0; jr < 4; ++jr) zc[jr] = zn[jr];
    }

    // prefetch next strip's first k32 BEFORE the epilogue
    if (strip < 3) {
      const ushort* zbn = zpk + (size_t)((rbase + 256) >> 4) * 4096 + lane * 8;
#pragma unroll
      for (int jr = 0; jr < 4; ++jr) zc[jr] = *(const short8*)(zbn + jr * 4096);
    }

    // epilogue: D row=code(q*4+reg), col=z-row(m16). 8-group g0 = q{0,1} regs,
    // g1 = q{2,3}. in-lane reg-max -> xor16 (8-max) -> xor32 (swap halves) -> pack.
#pragma unroll
    for (int jr = 0; jr < 4; ++jr) {
      uint pk[4];
#pragma unroll
      for (int ic = 0; ic < 4; ++ic) {
        float m = fmaxf(fmaxf(acc[ic][jr][0], acc[ic][jr][1]),
                        fmaxf(acc[ic][jr][2], acc[ic][jr][3]));
        m = fmaxf(m, __shfl_xor(m, 16, 64));     // 8-group max (own half)
        const float o = __shfl_xor(m, 32, 64);   // other half's 8-group max
        const float glo = (q & 2) ? o : m;
        const float ghi = (q & 2) ? m : o;
        pk[ic] = (uint)f2bf(glo) | ((uint)f2bf(ghi) << 16);
      }
      const uint sv = (q == 0) ? pk[0] : (q == 1) ? pk[1] : (q == 2) ? pk[2] : pk[3];
      gmax[(size_t)(rbase + jr * 16 + m16) * 512 + colb * 4 + q] = sv;
    }
  }
}

// ---------------- wave-per-row: global max over 1024 8-groups -> exact rescore of hits
// Hit compaction is ballot-prefix based: slot order is a pure function of (j, half,
// lane) — bit-identical across replays regardless of wave scheduling (r10 fix).
__global__ __launch_bounds__(256) void select_rescore(const uint* __restrict__ gmax,
                                                      const float* __restrict__ zt,
                                                      const float* __restrict__ emb,
                                                      const float* __restrict__ sumz,
                                                      u64* __restrict__ best) {
  const int t = threadIdx.x, w = t >> 6, lane = t & 63;
  const int n = (blockIdx.x << 2) + w;     // one wave per row, no __syncthreads
  __shared__ float zrow[4][256];
  __shared__ ushort hits[4][128];
  ((float4*)zrow[w])[lane] = ((const float4*)(zt + (size_t)n * 256))[lane];
  const uint4 r0 = ((const uint4*)(gmax + (size_t)n * 512))[lane];        // u32 4l..
  const uint4 r1 = ((const uint4*)(gmax + (size_t)n * 512))[lane + 64];   // 256+4l..
  const uint uv[8] = {r0.x, r0.y, r0.z, r0.w, r1.x, r1.y, r1.z, r1.w};
  float m = -INFINITY;
#pragma unroll
  for (int j = 0; j < 8; ++j) {
    m = fmaxf(m, __uint_as_float(uv[j] << 16));
    m = fmaxf(m, __uint_as_float(uv[j] & 0xffff0000u));
  }
#pragma unroll
  for (int off = 1; off < 64; off <<= 1) m = fmaxf(m, __shfl_xor(m, off, 64));
  const float thr = m - DOT_MARGIN;
  const u64 below = (1ull << lane) - 1ull;
  int base = 0;
#pragma unroll
  for (int j = 0; j < 8; ++j) {
    const int ui = (j < 4) ? lane * 4 + j : 256 + lane * 4 + (j - 4);
    {
      const bool hit = __uint_as_float(uv[j] << 16) >= thr;
      const u64 msk = __ballot(hit);
      if (hit) {
        const int p = base + (int)__popcll(msk & below);
        if (p < 128) hits[w][p] = (ushort)(ui * 2);
      }
      base += (int)__popcll(msk);
    }
    {
      const bool hit = __uint_as_float(uv[j] & 0xffff0000u) >= thr;
      const u64 msk = __ballot(hit);
      if (hit) {
        const int p = base + (int)__popcll(msk & below);
        if (p < 128) hits[w][p] = (ushort)(ui * 2 + 1);
      }
      base += (int)__popcll(msk);
    }
  }
  __threadfence_block();
  int K = base > 128 ? 128 : base;
  const float sz = sumz[n];
  u64 bk = ~0ull;
  for (int id = lane; id < K * 8; id += 64) {
    const int gid = hits[w][id >> 3];
    const int u = gid >> 1, h = gid & 1;
    const int c = (u >> 3) * 128 + (u & 7) * 16 + h * 8 + (id & 7);
    const float4* ea = (const float4*)(emb + c * 256);
    const float4* za = (const float4*)zrow[w];
    float sdot = 0.f, se = 0.f;
#pragma unroll 8
    for (int k = 0; k < 64; ++k) {          // validated sequential-k fp32 numerics
      const float4 a = za[k], e = ea[k];
      sdot = fmaf(a.x, e.x, sdot); sdot = fmaf(a.y, e.y, sdot);
      sdot = fmaf(a.z, e.z, sdot); sdot = fmaf(a.w, e.w, sdot);
      se = fmaf(e.x, e.x, se); se = fmaf(e.y, e.y, se);
      se = fmaf(e.z, e.z, se); se = fmaf(e.w, e.w, se);
    }
    const float d = (sz + se) - 2.f * sdot;  // matches ref: (sumz+sume) - 2*dot
    const u64 key = ((u64)ford(d) << 32) | (uint)c;
    if (key < bk) bk = key;
  }
#pragma unroll
  for (int off = 1; off < 64; off <<= 1) {
    const u64 o = (((u64)(uint)__shfl_xor((int)(bk >> 32), off, 64)) << 32) |
                  (uint)__shfl_xor((int)(bk & 0xffffffffu), off, 64);
    if (o < bk) bk = o;
  }
  if (lane == 0) best[n] = bk;              // single owner, plain store
}

// ---------------- gather z_q, idx, loss + fused finalize (done-counter)
__global__ __launch_bounds__(256) void gather_kernel(const float* __restrict__ z,
                                                     const float* __restrict__ emb,
                                                     const u64* __restrict__ best,
                                                     float* __restrict__ out,
                                                     double* __restrict__ loss_acc,
                                                     uint* __restrict__ done) {
  const int t = threadIdx.x;
  const int n0 = blockIdx.x << 6;
  const int n = n0 + (t & 63);
  const int idx = (int)(best[n] & 0xffffffffull);
  const int b_i = n >> 10, hw = n & 1023;
  const int c0 = t >> 6;
  const float* zb = z + b_i * 262144 + hw;
  float* ob = out + b_i * 262144 + hw;
  const float* eb = emb + idx * 256;
  float lsum = 0.f;
#pragma unroll 4
  for (int c = c0; c < 256; c += 4) {
    const float ev = eb[c];
    const float zv = zb[c << 10];
    ob[c << 10] = ev;
    const float d = ev - zv;
    lsum += d * d;
  }
  if (c0 == 0) out[4194305 + n] = (float)idx;
#pragma unroll
  for (int off = 32; off; off >>= 1) lsum += __shfl_down(lsum, off, 64);
  __shared__ double wsum[4];
  if ((t & 63) == 0) wsum[t >> 6] = (double)lsum;
  __syncthreads();
  if (t == 0) {
    atomicAdd(loss_acc, wsum[0] + wsum[1] + wsum[2] + wsum[3]);
    __threadfence();
    if (atomicAdd(done, 1u) == 255u) {       // last of 256 blocks
      __threadfence();
      out[4194304] = (float)(1.25 * (*(volatile double*)loss_acc) / 4194304.0);
    }
  }
}

// ---------------- launch
extern "C" void kernel_launch(void* const* d_in, const int* in_sizes, int n_in,
                              void* d_out, int out_size, void* d_ws, size_t ws_size,
                              hipStream_t stream) {
  const float* z = (const float*)d_in[0];
  const float* emb = (const float*)d_in[1];
  float* out = (float*)d_out;
  char* ws = (char*)d_ws;
  float* zt = (float*)(ws + WS_ZT);
  ushort* zpk = (ushort*)(ws + WS_ZPK);
  ushort* epk = (ushort*)(ws + WS_EPK);
  float* sumz = (float*)(ws + WS_SUMZ);
  uint* gmax = (uint*)(ws + WS_GMAX);
  u64* best = (u64*)(ws + WS_BEST);
  double* loss_acc = (double*)(ws + WS_LOSS);
  uint* done = (uint*)(ws + WS_LOSS + 8);

  hipMemsetAsync(ws + WS_LOSS, 0, 16, stream);   // loss_acc + done ctr
  prep_z<<<1024, 256, 0, stream>>>(z, zt, zpk);
  prep_e<<<1024, 256, 0, stream>>>(emb, epk);
  zsum_kernel<<<64, 256, 0, stream>>>(z, sumz);
  gemm_screen<<<2048, 256, 0, stream>>>(zpk, epk, gmax);
  select_rescore<<<4096, 256, 0, stream>>>(gmax, zt, emb, sumz, best);
  gather_kernel<<<256, 256, 0, stream>>>(z, emb, best, out, loss_acc, done);
}

// Round 2
// 259.901 us; speedup vs baseline: 1.1087x; 1.1087x over previous
//
#include <hip/hip_runtime.h>
#include <math.h>

typedef unsigned int uint;
typedef unsigned short ushort;
typedef unsigned long long u64;
typedef __attribute__((ext_vector_type(8))) short short8;
typedef __attribute__((ext_vector_type(4))) float f32x4;

// Problem: z (16,256,32,32) fp32, emb (8192,256) fp32. N=16384 rows, K=256, C=8192 codes.
// out (fp32): [0,4194304) z_q (b,c,h,w) | [4194304] loss | [4194305,+16384) idx as float
//
// Pipeline: bf16-MFMA screen (codebook 64-code/32KB panel LDS-resident, barrier-free
// K-loop, 2-deep z prefetch) -> per-row per-8code-group max, 2 groups packed bf16 in
// u32 (gmax[n][512], XCD-grouped columns) -> wave-per-row select within margin of
// global max -> exact fp32 rescore (d = fl32((sumz + sume) - 2*dot)) -> u64
// (score|idx) min, lowest-index ties.
//
// HW lesson (round 9): __launch_bounds__ 2nd arg acted as CUDA min-BLOCKS/CU here
// ((512,4) -> 64 VGPR -> acc spilled -> 525MB scratch FETCH). Never cap below live set.
// HW lesson (round 10): LDS atomicAdd hit compaction was scheduling-dependent ->
// ballot+popc prefix compaction (deterministic slots, no LDS atomics).
// Round 11 theory: gemm_screen latency-bound (MfmaUtil 21.5%, all pipes idle).
// 1-step z prefetch (~78-234 cyc coverage) << L3 latency (~500-900 cyc) because the
// 8MB z stream misses the 4MB XCD L2 (evicted by 64MB of 2x-amplified gmax writes
// whose 64B lines straddled XCDs). Fixes: 2-deep z prefetch, XCD-grouped gmax
// columns (write combining), non-temporal gmax stores (no L2 pollution).
//
// ws: zt fp32[16384][256] @0 | zpk 8MB | epk 4MB | sumz | gmax u32[16384][512] | best | loss,ctr
#define WS_ZT   0ull
#define WS_ZPK  16777216ull
#define WS_EPK  25165824ull
#define WS_SUMZ 29360128ull
#define WS_GMAX 29425664ull
#define WS_BEST 62980096ull
#define WS_LOSS 63111168ull

#define DOT_MARGIN 1.5e-4f  // r9 bound: 2*eps_screen + bf16 store ulp ~4.1e-5; >3.5x safety

__device__ __forceinline__ ushort f2bf(float f) {           // RNE fp32->bf16
  uint b = __float_as_uint(f);
  b += 0x7fffu + ((b >> 16) & 1u);
  return (ushort)(b >> 16);
}
__device__ __forceinline__ uint ford(float f) {             // orderable uint
  uint b = __float_as_uint(f);
  return (b & 0x80000000u) ? ~b : (b | 0x80000000u);
}
__device__ __forceinline__ void gload_lds16(const void* g, void* l) {
  __builtin_amdgcn_global_load_lds(
      (const __attribute__((address_space(1))) unsigned int*)g,
      (__attribute__((address_space(3))) unsigned int*)l, 16, 0, 0);
}

// ---------------- prep: zt[n][k] fp32 + zpk fragment-packed bf16 (validated)
__global__ __launch_bounds__(256) void prep_z(const float* __restrict__ z,
                                              float* __restrict__ zt,
                                              ushort* __restrict__ zpk) {
  __shared__ float tile[64][65];
  const int bid = blockIdx.x;
  const int kt = bid & 3, hwt = (bid >> 2) & 15, b = bid >> 6;
  const int t = threadIdx.x, lane = t & 63, grp = t >> 6;
  const float* src = z + b * 262144 + (kt * 64) * 1024 + hwt * 64;
  for (int kk = grp; kk < 64; kk += 4)
    tile[kk][lane] = src[kk * 1024 + lane];                 // coalesced over hw
  __syncthreads();
  for (int rr = grp; rr < 64; rr += 4) {                    // zt: coalesced over k
    const int n = b * 1024 + hwt * 64 + rr;
    zt[n * 256 + kt * 64 + lane] = tile[lane][rr];
  }
  for (int u = t; u < 512; u += 256) {                      // zpk: 16B frag pieces
    const int n_loc = u & 63, kg = u >> 6;
    const int n = b * 1024 + hwt * 64 + n_loc;
    const int k0 = kt * 64 + kg * 8;
    short8 s;
#pragma unroll
    for (int j = 0; j < 8; ++j) s[j] = (short)f2bf(tile[kg * 8 + j][n_loc]);
    *(short8*)(zpk + (size_t)(n >> 4) * 4096 + (k0 >> 5) * 512 +
               ((k0 >> 3) & 3) * 128 + (n & 15) * 8) = s;
  }
}

// ---------------- prep: epk fragment-packed bf16 codebook (validated)
__global__ __launch_bounds__(256) void prep_e(const float* __restrict__ emb,
                                              ushort* __restrict__ epk) {
  const int u = blockIdx.x * 256 + threadIdx.x;             // 262144 threads
  const int c = u >> 5, k0 = (u & 31) * 8;
  const float4 v0 = *(const float4*)(emb + c * 256 + k0);
  const float4 v1 = *(const float4*)(emb + c * 256 + k0 + 4);
  short8 s;
  s[0] = (short)f2bf(v0.x); s[1] = (short)f2bf(v0.y);
  s[2] = (short)f2bf(v0.z); s[3] = (short)f2bf(v0.w);
  s[4] = (short)f2bf(v1.x); s[5] = (short)f2bf(v1.y);
  s[6] = (short)f2bf(v1.z); s[7] = (short)f2bf(v1.w);
  *(short8*)(epk + (size_t)(c >> 4) * 4096 + (k0 >> 5) * 512 +
             ((k0 >> 3) & 3) * 128 + (c & 15) * 8) = s;
}

// ---------------- sumz[n] = ||z_n||^2, sequential-k fp32 (validated numerics)
__global__ __launch_bounds__(256) void zsum_kernel(const float* __restrict__ z,
                                                   float* __restrict__ sumz) {
  const int n = (blockIdx.x << 8) + threadIdx.x;
  const int b = n >> 10, hw = n & 1023;
  const float* zb = z + b * 262144 + hw;
  float s = 0.f;
#pragma unroll 8
  for (int c = 0; c < 256; ++c) { const float v = zb[c << 10]; s += v * v; }
  sumz[n] = s;
}

// ---------------- screening GEMM: 64-code (32 KB) panel LDS-resident, barrier-free
// 256 threads / 4 waves; all waves share the 4 code-tiles, wave w owns row-quarter w.
// Block: 1024 rows x 64 codes, 4 strips of 256 rows; per wave-strip 64 rows x 64 codes.
// grid 2048 = 8 XCD x 16 colb x 16 rowg; 2-deep z prefetch (z0/z1/z2 rotation) so
// z-load latency (~L2 200cyc after NT-store fix) is covered by ~2 k-steps of MFMA.
__global__ __launch_bounds__(256) void gemm_screen(const ushort* __restrict__ zpk,
                                                   const ushort* __restrict__ epk,
                                                   uint* __restrict__ gmax) {
  __shared__ ushort Cs[16384];   // 32 KB: 32 frags x 1KB, frag f = c16loc*8 + k32
  const int t = threadIdx.x;
  const int w = t >> 6, lane = t & 63;
  const int bid = blockIdx.x;
  const int x = bid & 7, y = bid >> 3;
  const int colb = (y & 15) * 8 + x;       // 0..127; XCD x owns 16 panels (512KB, L2)
  const int rowg = y >> 4;                 // 0..15
  const int n0 = rowg << 10;
  const int m16 = lane & 15, q = lane >> 4;
  // gmax column, XCD-grouped: a 64B line = 4 adjacent (y&15) panels of the SAME x
  // (same XCD) -> concurrent blocks write-combine full lines in their own L2.
  const int cix = x * 64 + (y & 15) * 4 + q;

  // stage code panel once: 8 coalesced 1KB DMAs per wave
#pragma unroll
  for (int f2 = 0; f2 < 8; ++f2) {
    const int f = w * 8 + f2;
    gload_lds16(epk + (size_t)colb * 16384 + f * 512 + lane * 8, (char*)Cs + f * 1024);
  }

  // prologue z loads (u=0,1) overlap the DMA drain at the barrier
  short8 z0[4], z1[4], z2[4];
  const ushort* zs0 = zpk + ((size_t)(n0 >> 4) + w * 4) * 4096 + lane * 8;
#pragma unroll
  for (int jr = 0; jr < 4; ++jr) z0[jr] = *(const short8*)(zs0 + jr * 4096);
#pragma unroll
  for (int jr = 0; jr < 4; ++jr) z1[jr] = *(const short8*)(zs0 + jr * 4096 + 512);
  __syncthreads();                         // only barrier in the kernel

  for (int strip = 0; strip < 4; ++strip) {
    const int rbase = n0 + strip * 256 + w * 64;
    const ushort* zb = zpk + (size_t)(rbase >> 4) * 4096 + lane * 8;
    const ushort* zbn = (strip < 3) ? (zb + 16 * 4096) : zb;  // next strip (clamped)
    f32x4 acc[4][4];                       // [ic][jr]
#pragma unroll
    for (int i = 0; i < 4; ++i)
#pragma unroll
      for (int j = 0; j < 4; ++j) acc[i][j] = {0.f, 0.f, 0.f, 0.f};

#pragma unroll
    for (int s32 = 0; s32 < 8; ++s32) {    // k32 steps over K=256
      // 2-deep prefetch: fragments for step u+2 (crosses into next strip at 6,7)
      const ushort* pf = (s32 < 6) ? (zb + (s32 + 2) * 512) : (zbn + (s32 - 6) * 512);
#pragma unroll
      for (int jr = 0; jr < 4; ++jr) z2[jr] = *(const short8*)(pf + jr * 4096);
      short8 cv[4];
#pragma unroll
      for (int ic = 0; ic < 4; ++ic)
        cv[ic] = *(const short8*)&Cs[(size_t)(ic * 8 + s32) * 512 + lane * 8];
#pragma unroll
      for (int ic = 0; ic < 4; ++ic)
#pragma unroll
        for (int jr = 0; jr < 4; ++jr)
          acc[ic][jr] = __builtin_amdgcn_mfma_f32_16x16x32_bf16(cv[ic], z0[jr],
                                                                acc[ic][jr], 0, 0, 0);
#pragma unroll
      for (int jr = 0; jr < 4; ++jr) { z0[jr] = z1[jr]; z1[jr] = z2[jr]; }
    }
    // after 8 rotations z0/z1 hold the next strip's u=0,1 fragments automatically

    // epilogue: D row=code(q*4+reg), col=z-row(m16). 8-group g0 = q{0,1} regs,
    // g1 = q{2,3}. in-lane reg-max -> xor16 (8-max) -> xor32 (swap halves) -> pack.
#pragma unroll
    for (int jr = 0; jr < 4; ++jr) {
      uint pk[4];
#pragma unroll
      for (int ic = 0; ic < 4; ++ic) {
        float m = fmaxf(fmaxf(acc[ic][jr][0], acc[ic][jr][1]),
                        fmaxf(acc[ic][jr][2], acc[ic][jr][3]));
        m = fmaxf(m, __shfl_xor(m, 16, 64));     // 8-group max (own half)
        const float o = __shfl_xor(m, 32, 64);   // other half's 8-group max
        const float glo = (q & 2) ? o : m;
        const float ghi = (q & 2) ? m : o;
        pk[ic] = (uint)f2bf(glo) | ((uint)f2bf(ghi) << 16);
      }
      const uint sv = (q == 0) ? pk[0] : (q == 1) ? pk[1] : (q == 2) ? pk[2] : pk[3];
      // non-temporal: gmax is write-once/read-later streaming -> don't evict z/epk
      __builtin_nontemporal_store(sv,
          &gmax[(size_t)(rbase + jr * 16 + m16) * 512 + cix]);
    }
  }
}

// ---------------- wave-per-row: global max over 1024 8-groups -> exact rescore of hits
// Hit compaction is ballot-prefix based: slot order is a pure function of (j, half,
// lane) — bit-identical across replays regardless of wave scheduling (r10 fix).
__global__ __launch_bounds__(256) void select_rescore(const uint* __restrict__ gmax,
                                                      const float* __restrict__ zt,
                                                      const float* __restrict__ emb,
                                                      const float* __restrict__ sumz,
                                                      u64* __restrict__ best) {
  const int t = threadIdx.x, w = t >> 6, lane = t & 63;
  const int n = (blockIdx.x << 2) + w;     // one wave per row, no __syncthreads
  __shared__ float zrow[4][256];
  __shared__ ushort hits[4][128];
  ((float4*)zrow[w])[lane] = ((const float4*)(zt + (size_t)n * 256))[lane];
  const uint4 r0 = ((const uint4*)(gmax + (size_t)n * 512))[lane];        // u32 4l..
  const uint4 r1 = ((const uint4*)(gmax + (size_t)n * 512))[lane + 64];   // 256+4l..
  const uint uv[8] = {r0.x, r0.y, r0.z, r0.w, r1.x, r1.y, r1.z, r1.w};
  float m = -INFINITY;
#pragma unroll
  for (int j = 0; j < 8; ++j) {
    m = fmaxf(m, __uint_as_float(uv[j] << 16));
    m = fmaxf(m, __uint_as_float(uv[j] & 0xffff0000u));
  }
#pragma unroll
  for (int off = 1; off < 64; off <<= 1) m = fmaxf(m, __shfl_xor(m, off, 64));
  const float thr = m - DOT_MARGIN;
  const u64 below = (1ull << lane) - 1ull;
  int base = 0;
#pragma unroll
  for (int j = 0; j < 8; ++j) {
    const int ui = (j < 4) ? lane * 4 + j : 256 + lane * 4 + (j - 4);
    {
      const bool hit = __uint_as_float(uv[j] << 16) >= thr;
      const u64 msk = __ballot(hit);
      if (hit) {
        const int p = base + (int)__popcll(msk & below);
        if (p < 128) hits[w][p] = (ushort)(ui * 2);
      }
      base += (int)__popcll(msk);
    }
    {
      const bool hit = __uint_as_float(uv[j] & 0xffff0000u) >= thr;
      const u64 msk = __ballot(hit);
      if (hit) {
        const int p = base + (int)__popcll(msk & below);
        if (p < 128) hits[w][p] = (ushort)(ui * 2 + 1);
      }
      base += (int)__popcll(msk);
    }
  }
  __threadfence_block();
  int K = base > 128 ? 128 : base;
  const float sz = sumz[n];
  u64 bk = ~0ull;
  for (int id = lane; id < K * 8; id += 64) {
    const int gid = hits[w][id >> 3];
    const int ci = gid >> 1, h = gid & 1;
    // inverse of gemm's XCD-grouped column map: ci = x*64 + yy*4 + q,
    // colb = yy*8 + x, code = colb*64 + q*16 + h*8 + j
    const int c = ((ci >> 2) & 15) * 512 + (ci >> 6) * 64 + (ci & 3) * 16 +
                  h * 8 + (id & 7);
    const float4* ea = (const float4*)(emb + c * 256);
    const float4* za = (const float4*)zrow[w];
    float sdot = 0.f, se = 0.f;
#pragma unroll 8
    for (int k = 0; k < 64; ++k) {          // validated sequential-k fp32 numerics
      const float4 a = za[k], e = ea[k];
      sdot = fmaf(a.x, e.x, sdot); sdot = fmaf(a.y, e.y, sdot);
      sdot = fmaf(a.z, e.z, sdot); sdot = fmaf(a.w, e.w, sdot);
      se = fmaf(e.x, e.x, se); se = fmaf(e.y, e.y, se);
      se = fmaf(e.z, e.z, se); se = fmaf(e.w, e.w, se);
    }
    const float d = (sz + se) - 2.f * sdot;  // matches ref: (sumz+sume) - 2*dot
    const u64 key = ((u64)ford(d) << 32) | (uint)c;
    if (key < bk) bk = key;
  }
#pragma unroll
  for (int off = 1; off < 64; off <<= 1) {
    const u64 o = (((u64)(uint)__shfl_xor((int)(bk >> 32), off, 64)) << 32) |
                  (uint)__shfl_xor((int)(bk & 0xffffffffu), off, 64);
    if (o < bk) bk = o;
  }
  if (lane == 0) best[n] = bk;              // single owner, plain store
}

// ---------------- gather z_q, idx, loss + fused finalize (done-counter)
__global__ __launch_bounds__(256) void gather_kernel(const float* __restrict__ z,
                                                     const float* __restrict__ emb,
                                                     const u64* __restrict__ best,
                                                     float* __restrict__ out,
                                                     double* __restrict__ loss_acc,
                                                     uint* __restrict__ done) {
  const int t = threadIdx.x;
  const int n0 = blockIdx.x << 6;
  const int n = n0 + (t & 63);
  const int idx = (int)(best[n] & 0xffffffffull);
  const int b_i = n >> 10, hw = n & 1023;
  const int c0 = t >> 6;
  const float* zb = z + b_i * 262144 + hw;
  float* ob = out + b_i * 262144 + hw;
  const float* eb = emb + idx * 256;
  float lsum = 0.f;
#pragma unroll 4
  for (int c = c0; c < 256; c += 4) {
    const float ev = eb[c];
    const float zv = zb[c << 10];
    ob[c << 10] = ev;
    const float d = ev - zv;
    lsum += d * d;
  }
  if (c0 == 0) out[4194305 + n] = (float)idx;
#pragma unroll
  for (int off = 32; off; off >>= 1) lsum += __shfl_down(lsum, off, 64);
  __shared__ double wsum[4];
  if ((t & 63) == 0) wsum[t >> 6] = (double)lsum;
  __syncthreads();
  if (t == 0) {
    atomicAdd(loss_acc, wsum[0] + wsum[1] + wsum[2] + wsum[3]);
    __threadfence();
    if (atomicAdd(done, 1u) == 255u) {       // last of 256 blocks
      __threadfence();
      out[4194304] = (float)(1.25 * (*(volatile double*)loss_acc) / 4194304.0);
    }
  }
}

// ---------------- launch
extern "C" void kernel_launch(void* const* d_in, const int* in_sizes, int n_in,
                              void* d_out, int out_size, void* d_ws, size_t ws_size,
                              hipStream_t stream) {
  const float* z = (const float*)d_in[0];
  const float* emb = (const float*)d_in[1];
  float* out = (float*)d_out;
  char* ws = (char*)d_ws;
  float* zt = (float*)(ws + WS_ZT);
  ushort* zpk = (ushort*)(ws + WS_ZPK);
  ushort* epk = (ushort*)(ws + WS_EPK);
  float* sumz = (float*)(ws + WS_SUMZ);
  uint* gmax = (uint*)(ws + WS_GMAX);
  u64* best = (u64*)(ws + WS_BEST);
  double* loss_acc = (double*)(ws + WS_LOSS);
  uint* done = (uint*)(ws + WS_LOSS + 8);

  hipMemsetAsync(ws + WS_LOSS, 0, 16, stream);   // loss_acc + done ctr
  prep_z<<<1024, 256, 0, stream>>>(z, zt, zpk);
  prep_e<<<1024, 256, 0, stream>>>(emb, epk);
  zsum_kernel<<<64, 256, 0, stream>>>(z, sumz);
  gemm_screen<<<2048, 256, 0, stream>>>(zpk, epk, gmax);
  select_rescore<<<4096, 256, 0, stream>>>(gmax, zt, emb, sumz, best);
  gather_kernel<<<256, 256, 0, stream>>>(z, emb, best, out, loss_acc, done);
}

// Round 3
// 249.501 us; speedup vs baseline: 1.1549x; 1.0417x over previous
//
#include <hip/hip_runtime.h>
#include <math.h>

typedef unsigned int uint;
typedef unsigned short ushort;
typedef unsigned long long u64;
typedef __attribute__((ext_vector_type(8))) short short8;
typedef __attribute__((ext_vector_type(4))) float f32x4;

// Problem: z (16,256,32,32) fp32, emb (8192,256) fp32. N=16384 rows, K=256, C=8192 codes.
// out (fp32): [0,4194304) z_q (b,c,h,w) | [4194304] loss | [4194305,+16384) idx as float
//
// Pipeline: fused prep (zt/zpk/epk/sumz) -> bf16-MFMA screen (codebook 64-code/32KB
// panel LDS-resident, barrier-free K-loop, 3-deep z prefetch) -> per-row per-8code-
// group max packed bf16 pairs (gmax[n][512], XCD-grouped columns) -> wave-per-row
// select within margin -> exact fp32 rescore (d = fl32((sumz+sume) - 2*dot)) -> u64
// (score|idx) min, lowest-index ties.
//
// HW lesson (r9): __launch_bounds__ 2nd arg cap below live set -> scratch spills.
// HW lesson (r10): LDS atomicAdd compaction is scheduling-dependent -> ballot+popc.
// HW lesson (r11): latency-bound screen: 2-deep reg prefetch + XCD-grouped gmax
// columns + better L2 locality took 127->97us (MfmaUtil 21.5->28.7, FETCH 49->35MB).
// HW lesson (r12): NT stores RAISED write amplification (65->75MB) - they bypass the
// L2 write-combining the cix layout targets, and vmcnt drains FIFO so slow HBM-bound
// NT stores at queue head stall every later z-load wait. Plain stores + L2 combining.
//
// ws: zt fp32[16384][256] @0 | zpk 8MB | epk 4MB | sumz | gmax u32[16384][512] | best | loss,ctr
#define WS_ZT   0ull
#define WS_ZPK  16777216ull
#define WS_EPK  25165824ull
#define WS_SUMZ 29360128ull
#define WS_GMAX 29425664ull
#define WS_BEST 62980096ull
#define WS_LOSS 63111168ull

#define DOT_MARGIN 1.5e-4f  // r9 bound: 2*eps_screen + bf16 store ulp ~4.1e-5; >3.5x safety

__device__ __forceinline__ ushort f2bf(float f) {           // RNE fp32->bf16
  uint b = __float_as_uint(f);
  b += 0x7fffu + ((b >> 16) & 1u);
  return (ushort)(b >> 16);
}
__device__ __forceinline__ uint ford(float f) {             // orderable uint
  uint b = __float_as_uint(f);
  return (b & 0x80000000u) ? ~b : (b | 0x80000000u);
}
__device__ __forceinline__ void gload_lds16(const void* g, void* l) {
  __builtin_amdgcn_global_load_lds(
      (const __attribute__((address_space(1))) unsigned int*)g,
      (__attribute__((address_space(3))) unsigned int*)l, 16, 0, 0);
}

// ---------------- fused prep: zt+zpk (blocks 0..1023), epk (1024..2047),
// sumz (2048..2111). Bodies verbatim from the validated split kernels; branch is
// block-uniform. One dispatch instead of three (saves 2 launch gaps, overlaps the
// independent memory phases).
__global__ __launch_bounds__(256) void prep_all(const float* __restrict__ z,
                                                const float* __restrict__ emb,
                                                float* __restrict__ zt,
                                                ushort* __restrict__ zpk,
                                                ushort* __restrict__ epk,
                                                float* __restrict__ sumz) {
  __shared__ float tile[64][65];
  const int bidg = blockIdx.x;
  const int t = threadIdx.x;
  if (bidg < 1024) {                                        // ---- prep_z
    const int bid = bidg;
    const int kt = bid & 3, hwt = (bid >> 2) & 15, b = bid >> 6;
    const int lane = t & 63, grp = t >> 6;
    const float* src = z + b * 262144 + (kt * 64) * 1024 + hwt * 64;
    for (int kk = grp; kk < 64; kk += 4)
      tile[kk][lane] = src[kk * 1024 + lane];               // coalesced over hw
    __syncthreads();
    for (int rr = grp; rr < 64; rr += 4) {                  // zt: coalesced over k
      const int n = b * 1024 + hwt * 64 + rr;
      zt[n * 256 + kt * 64 + lane] = tile[lane][rr];
    }
    for (int u = t; u < 512; u += 256) {                    // zpk: 16B frag pieces
      const int n_loc = u & 63, kg = u >> 6;
      const int n = b * 1024 + hwt * 64 + n_loc;
      const int k0 = kt * 64 + kg * 8;
      short8 s;
#pragma unroll
      for (int j = 0; j < 8; ++j) s[j] = (short)f2bf(tile[kg * 8 + j][n_loc]);
      *(short8*)(zpk + (size_t)(n >> 4) * 4096 + (k0 >> 5) * 512 +
                 ((k0 >> 3) & 3) * 128 + (n & 15) * 8) = s;
    }
  } else if (bidg < 2048) {                                 // ---- prep_e
    const int u = (bidg - 1024) * 256 + t;                  // 262144 threads
    const int c = u >> 5, k0 = (u & 31) * 8;
    const float4 v0 = *(const float4*)(emb + c * 256 + k0);
    const float4 v1 = *(const float4*)(emb + c * 256 + k0 + 4);
    short8 s;
    s[0] = (short)f2bf(v0.x); s[1] = (short)f2bf(v0.y);
    s[2] = (short)f2bf(v0.z); s[3] = (short)f2bf(v0.w);
    s[4] = (short)f2bf(v1.x); s[5] = (short)f2bf(v1.y);
    s[6] = (short)f2bf(v1.z); s[7] = (short)f2bf(v1.w);
    *(short8*)(epk + (size_t)(c >> 4) * 4096 + (k0 >> 5) * 512 +
               ((k0 >> 3) & 3) * 128 + (c & 15) * 8) = s;
  } else {                                                  // ---- zsum (verbatim)
    const int n = ((bidg - 2048) << 8) + t;
    const int b = n >> 10, hw = n & 1023;
    const float* zb = z + b * 262144 + hw;
    float s = 0.f;
#pragma unroll 8
    for (int c = 0; c < 256; ++c) { const float v = zb[c << 10]; s += v * v; }
    sumz[n] = s;
  }
}

// ---------------- screening GEMM: 64-code (32 KB) panel LDS-resident, barrier-free
// 256 threads / 4 waves; all waves share the 4 code-tiles, wave w owns row-quarter w.
// Block: 1024 rows x 64 codes, 4 strips of 256 rows; per wave-strip 64 rows x 64 codes.
// grid 2048 = 8 XCD x 16 colb x 16 rowg; 3-deep z prefetch (z0..z3 rotation over the
// flattened 32-step k-sequence) so L3/HBM latency is covered by ~3 k-steps of MFMA.
__global__ __launch_bounds__(256) void gemm_screen(const ushort* __restrict__ zpk,
                                                   const ushort* __restrict__ epk,
                                                   uint* __restrict__ gmax) {
  __shared__ ushort Cs[16384];   // 32 KB: 32 frags x 1KB, frag f = c16loc*8 + k32
  const int t = threadIdx.x;
  const int w = t >> 6, lane = t & 63;
  const int bid = blockIdx.x;
  const int x = bid & 7, y = bid >> 3;
  const int colb = (y & 15) * 8 + x;       // 0..127; XCD x owns 16 panels (512KB, L2)
  const int rowg = y >> 4;                 // 0..15
  const int n0 = rowg << 10;
  const int m16 = lane & 15, q = lane >> 4;
  // gmax column, XCD-grouped: a 64B line = 4 adjacent (y&15) panels of the SAME x
  // (same XCD) -> concurrent blocks write-combine full lines in their own L2.
  const int cix = x * 64 + (y & 15) * 4 + q;

  // stage code panel once: 8 coalesced 1KB DMAs per wave
#pragma unroll
  for (int f2 = 0; f2 < 8; ++f2) {
    const int f = w * 8 + f2;
    gload_lds16(epk + (size_t)colb * 16384 + f * 512 + lane * 8, (char*)Cs + f * 1024);
  }

  // z fragment address for flattened step v (0..31), row-frag jr:
  //   zw + ((v>>3)*16 + jr)*4096 + (v&7)*512
  const ushort* zw = zpk + ((size_t)(n0 >> 4) + w * 4) * 4096 + lane * 8;

  // prologue: 3-deep pipeline primed (overlaps the DMA drain at the barrier)
  short8 z0[4], z1[4], z2[4], z3[4];
#pragma unroll
  for (int jr = 0; jr < 4; ++jr) z0[jr] = *(const short8*)(zw + jr * 4096);
#pragma unroll
  for (int jr = 0; jr < 4; ++jr) z1[jr] = *(const short8*)(zw + jr * 4096 + 512);
#pragma unroll
  for (int jr = 0; jr < 4; ++jr) z2[jr] = *(const short8*)(zw + jr * 4096 + 1024);
  __syncthreads();                         // only barrier in the kernel

  for (int strip = 0; strip < 4; ++strip) {
    const int rbase = n0 + strip * 256 + w * 64;
    f32x4 acc[4][4];                       // [ic][jr]
#pragma unroll
    for (int i = 0; i < 4; ++i)
#pragma unroll
      for (int j = 0; j < 4; ++j) acc[i][j] = {0.f, 0.f, 0.f, 0.f};

#pragma unroll
    for (int s32 = 0; s32 < 8; ++s32) {    // k32 steps over K=256
      // 3-deep prefetch: fragments for flattened step v+3 (clamped at the tail)
      const int v = strip * 8 + s32 + 3;
      const int vv = v > 31 ? 31 : v;
      const ushort* pf = zw + ((size_t)(vv >> 3) * 16) * 4096 + (vv & 7) * 512;
#pragma unroll
      for (int jr = 0; jr < 4; ++jr) z3[jr] = *(const short8*)(pf + jr * 4096);
      short8 cv[4];
#pragma unroll
      for (int ic = 0; ic < 4; ++ic)
        cv[ic] = *(const short8*)&Cs[(size_t)(ic * 8 + s32) * 512 + lane * 8];
#pragma unroll
      for (int ic = 0; ic < 4; ++ic)
#pragma unroll
        for (int jr = 0; jr < 4; ++jr)
          acc[ic][jr] = __builtin_amdgcn_mfma_f32_16x16x32_bf16(cv[ic], z0[jr],
                                                                acc[ic][jr], 0, 0, 0);
#pragma unroll
      for (int jr = 0; jr < 4; ++jr) {
        z0[jr] = z1[jr]; z1[jr] = z2[jr]; z2[jr] = z3[jr];
      }
    }
    // after 8 rotations z0/z1/z2 hold the next strip's first fragments automatically

    // epilogue: D row=code(q*4+reg), col=z-row(m16). 8-group g0 = q{0,1} regs,
    // g1 = q{2,3}. in-lane reg-max -> xor16 (8-max) -> xor32 (swap halves) -> pack.
#pragma unroll
    for (int jr = 0; jr < 4; ++jr) {
      uint pk[4];
#pragma unroll
      for (int ic = 0; ic < 4; ++ic) {
        float m = fmaxf(fmaxf(acc[ic][jr][0], acc[ic][jr][1]),
                        fmaxf(acc[ic][jr][2], acc[ic][jr][3]));
        m = fmaxf(m, __shfl_xor(m, 16, 64));     // 8-group max (own half)
        const float o = __shfl_xor(m, 32, 64);   // other half's 8-group max
        const float glo = (q & 2) ? o : m;
        const float ghi = (q & 2) ? m : o;
        pk[ic] = (uint)f2bf(glo) | ((uint)f2bf(ghi) << 16);
      }
      const uint sv = (q == 0) ? pk[0] : (q == 1) ? pk[1] : (q == 2) ? pk[2] : pk[3];
      // plain store: completes in L2 (fast vmcnt retirement; no FIFO poisoning of
      // later z-load waits) and write-combines with same-XCD neighbors (cix layout)
      gmax[(size_t)(rbase + jr * 16 + m16) * 512 + cix] = sv;
    }
  }
}

// ---------------- wave-per-row: global max over 1024 8-groups -> exact rescore of hits
// Hit compaction is ballot-prefix based: slot order is a pure function of (j, half,
// lane) — bit-identical across replays regardless of wave scheduling (r10 fix).
__global__ __launch_bounds__(256) void select_rescore(const uint* __restrict__ gmax,
                                                      const float* __restrict__ zt,
                                                      const float* __restrict__ emb,
                                                      const float* __restrict__ sumz,
                                                      u64* __restrict__ best) {
  const int t = threadIdx.x, w = t >> 6, lane = t & 63;
  const int n = (blockIdx.x << 2) + w;     // one wave per row, no __syncthreads
  __shared__ float zrow[4][256];
  __shared__ ushort hits[4][128];
  ((float4*)zrow[w])[lane] = ((const float4*)(zt + (size_t)n * 256))[lane];
  const uint4 r0 = ((const uint4*)(gmax + (size_t)n * 512))[lane];        // u32 4l..
  const uint4 r1 = ((const uint4*)(gmax + (size_t)n * 512))[lane + 64];   // 256+4l..
  const uint uv[8] = {r0.x, r0.y, r0.z, r0.w, r1.x, r1.y, r1.z, r1.w};
  float m = -INFINITY;
#pragma unroll
  for (int j = 0; j < 8; ++j) {
    m = fmaxf(m, __uint_as_float(uv[j] << 16));
    m = fmaxf(m, __uint_as_float(uv[j] & 0xffff0000u));
  }
#pragma unroll
  for (int off = 1; off < 64; off <<= 1) m = fmaxf(m, __shfl_xor(m, off, 64));
  const float thr = m - DOT_MARGIN;
  const u64 below = (1ull << lane) - 1ull;
  int base = 0;
#pragma unroll
  for (int j = 0; j < 8; ++j) {
    const int ui = (j < 4) ? lane * 4 + j : 256 + lane * 4 + (j - 4);
    {
      const bool hit = __uint_as_float(uv[j] << 16) >= thr;
      const u64 msk = __ballot(hit);
      if (hit) {
        const int p = base + (int)__popcll(msk & below);
        if (p < 128) hits[w][p] = (ushort)(ui * 2);
      }
      base += (int)__popcll(msk);
    }
    {
      const bool hit = __uint_as_float(uv[j] & 0xffff0000u) >= thr;
      const u64 msk = __ballot(hit);
      if (hit) {
        const int p = base + (int)__popcll(msk & below);
        if (p < 128) hits[w][p] = (ushort)(ui * 2 + 1);
      }
      base += (int)__popcll(msk);
    }
  }
  __threadfence_block();
  int K = base > 128 ? 128 : base;
  const float sz = sumz[n];
  u64 bk = ~0ull;
  for (int id = lane; id < K * 8; id += 64) {
    const int gid = hits[w][id >> 3];
    const int ci = gid >> 1, h = gid & 1;
    // inverse of gemm's XCD-grouped column map: ci = x*64 + yy*4 + q,
    // colb = yy*8 + x, code = colb*64 + q*16 + h*8 + j
    const int c = ((ci >> 2) & 15) * 512 + (ci >> 6) * 64 + (ci & 3) * 16 +
                  h * 8 + (id & 7);
    const float4* ea = (const float4*)(emb + c * 256);
    const float4* za = (const float4*)zrow[w];
    float sdot = 0.f, se = 0.f;
#pragma unroll 8
    for (int k = 0; k < 64; ++k) {          // validated sequential-k fp32 numerics
      const float4 a = za[k], e = ea[k];
      sdot = fmaf(a.x, e.x, sdot); sdot = fmaf(a.y, e.y, sdot);
      sdot = fmaf(a.z, e.z, sdot); sdot = fmaf(a.w, e.w, sdot);
      se = fmaf(e.x, e.x, se); se = fmaf(e.y, e.y, se);
      se = fmaf(e.z, e.z, se); se = fmaf(e.w, e.w, se);
    }
    const float d = (sz + se) - 2.f * sdot;  // matches ref: (sumz+sume) - 2*dot
    const u64 key = ((u64)ford(d) << 32) | (uint)c;
    if (key < bk) bk = key;
  }
#pragma unroll
  for (int off = 1; off < 64; off <<= 1) {
    const u64 o = (((u64)(uint)__shfl_xor((int)(bk >> 32), off, 64)) << 32) |
                  (uint)__shfl_xor((int)(bk & 0xffffffffu), off, 64);
    if (o < bk) bk = o;
  }
  if (lane == 0) best[n] = bk;              // single owner, plain store
}

// ---------------- gather z_q, idx, loss + fused finalize (done-counter)
__global__ __launch_bounds__(256) void gather_kernel(const float* __restrict__ z,
                                                     const float* __restrict__ emb,
                                                     const u64* __restrict__ best,
                                                     float* __restrict__ out,
                                                     double* __restrict__ loss_acc,
                                                     uint* __restrict__ done) {
  const int t = threadIdx.x;
  const int n0 = blockIdx.x << 6;
  const int n = n0 + (t & 63);
  const int idx = (int)(best[n] & 0xffffffffull);
  const int b_i = n >> 10, hw = n & 1023;
  const int c0 = t >> 6;
  const float* zb = z + b_i * 262144 + hw;
  float* ob = out + b_i * 262144 + hw;
  const float* eb = emb + idx * 256;
  float lsum = 0.f;
#pragma unroll 4
  for (int c = c0; c < 256; c += 4) {
    const float ev = eb[c];
    const float zv = zb[c << 10];
    ob[c << 10] = ev;
    const float d = ev - zv;
    lsum += d * d;
  }
  if (c0 == 0) out[4194305 + n] = (float)idx;
#pragma unroll
  for (int off = 32; off; off >>= 1) lsum += __shfl_down(lsum, off, 64);
  __shared__ double wsum[4];
  if ((t & 63) == 0) wsum[t >> 6] = (double)lsum;
  __syncthreads();
  if (t == 0) {
    atomicAdd(loss_acc, wsum[0] + wsum[1] + wsum[2] + wsum[3]);
    __threadfence();
    if (atomicAdd(done, 1u) == 255u) {       // last of 256 blocks
      __threadfence();
      out[4194304] = (float)(1.25 * (*(volatile double*)loss_acc) / 4194304.0);
    }
  }
}

// ---------------- launch
extern "C" void kernel_launch(void* const* d_in, const int* in_sizes, int n_in,
                              void* d_out, int out_size, void* d_ws, size_t ws_size,
                              hipStream_t stream) {
  const float* z = (const float*)d_in[0];
  const float* emb = (const float*)d_in[1];
  float* out = (float*)d_out;
  char* ws = (char*)d_ws;
  float* zt = (float*)(ws + WS_ZT);
  ushort* zpk = (ushort*)(ws + WS_ZPK);
  ushort* epk = (ushort*)(ws + WS_EPK);
  float* sumz = (float*)(ws + WS_SUMZ);
  uint* gmax = (uint*)(ws + WS_GMAX);
  u64* best = (u64*)(ws + WS_BEST);
  double* loss_acc = (double*)(ws + WS_LOSS);
  uint* done = (uint*)(ws + WS_LOSS + 8);

  hipMemsetAsync(ws + WS_LOSS, 0, 16, stream);   // loss_acc + done ctr
  prep_all<<<2112, 256, 0, stream>>>(z, emb, zt, zpk, epk, sumz);
  gemm_screen<<<2048, 256, 0, stream>>>(zpk, epk, gmax);
  select_rescore<<<4096, 256, 0, stream>>>(gmax, zt, emb, sumz, best);
  gather_kernel<<<256, 256, 0, stream>>>(z, emb, best, out, loss_acc, done);
}

// Round 4
// 234.109 us; speedup vs baseline: 1.2308x; 1.0657x over previous
//
#include <hip/hip_runtime.h>
#include <math.h>

typedef unsigned int uint;
typedef unsigned short ushort;
typedef unsigned long long u64;
typedef __attribute__((ext_vector_type(8))) short short8;
typedef __attribute__((ext_vector_type(4))) float f32x4;

// Problem: z (16,256,32,32) fp32, emb (8192,256) fp32. N=16384 rows, K=256, C=8192 codes.
// out (fp32): [0,4194304) z_q (b,c,h,w) | [4194304] loss | [4194305,+16384) idx as float
//
// Pipeline: fused prep (zt/zpk/epk/sumz) -> bf16-MFMA screen (codebook 64-code/32KB
// panel LDS-resident, barrier-free fully-unrolled K-loop, 3-step-ahead static
// prefetch) -> per-row per-8code-group max packed bf16 pairs (gmax[n][512],
// XCD-grouped columns) -> wave-per-row select within margin -> exact fp32 rescore
// (d = fl32((sumz+sume) - 2*dot)) -> u64 (score|idx) min, lowest-index ties.
//
// HW lesson (r9): __launch_bounds__ 2nd arg cap below live set -> scratch spills.
// HW lesson (r10): LDS atomicAdd compaction is scheduling-dependent -> ballot+popc.
// HW lesson (r11): latency-bound screen: reg prefetch + XCD-grouped gmax cols.
// HW lesson (r12): NT stores RAISED write amplification (65->75MB, bypass L2
// write-combining) and poisoned vmcnt FIFO. Plain stores + cix: WRITE exactly 32MB.
// HW lesson (r13): dur x MfmaUtil constant across r2/r3 (~2785): MFMA work fixed,
// all else stall. Pipeline register ROTATION (48 v_mov/step at 3-deep) out-issued
// the 16 MFMAs/step (78cy) -> VALU competed with MFMA issue. Fix: full unroll +
// static zf[32] indexing, zero copies.
//
// ws: zt fp32[16384][256] @0 | zpk 8MB | epk 4MB | sumz | gmax u32[16384][512] | best | loss,ctr
#define WS_ZT   0ull
#define WS_ZPK  16777216ull
#define WS_EPK  25165824ull
#define WS_SUMZ 29360128ull
#define WS_GMAX 29425664ull
#define WS_BEST 62980096ull
#define WS_LOSS 63111168ull

#define DOT_MARGIN 1.5e-4f  // r9 bound: 2*eps_screen + bf16 store ulp ~4.1e-5; >3.5x safety

__device__ __forceinline__ ushort f2bf(float f) {           // RNE fp32->bf16
  uint b = __float_as_uint(f);
  b += 0x7fffu + ((b >> 16) & 1u);
  return (ushort)(b >> 16);
}
__device__ __forceinline__ uint ford(float f) {             // orderable uint
  uint b = __float_as_uint(f);
  return (b & 0x80000000u) ? ~b : (b | 0x80000000u);
}
__device__ __forceinline__ void gload_lds16(const void* g, void* l) {
  __builtin_amdgcn_global_load_lds(
      (const __attribute__((address_space(1))) unsigned int*)g,
      (__attribute__((address_space(3))) unsigned int*)l, 16, 0, 0);
}

// ---------------- fused prep: zt+zpk (blocks 0..1023), epk (1024..2047),
// sumz (2048..2111). Bodies verbatim from the validated split kernels; branch is
// block-uniform.
__global__ __launch_bounds__(256) void prep_all(const float* __restrict__ z,
                                                const float* __restrict__ emb,
                                                float* __restrict__ zt,
                                                ushort* __restrict__ zpk,
                                                ushort* __restrict__ epk,
                                                float* __restrict__ sumz) {
  __shared__ float tile[64][65];
  const int bidg = blockIdx.x;
  const int t = threadIdx.x;
  if (bidg < 1024) {                                        // ---- prep_z
    const int bid = bidg;
    const int kt = bid & 3, hwt = (bid >> 2) & 15, b = bid >> 6;
    const int lane = t & 63, grp = t >> 6;
    const float* src = z + b * 262144 + (kt * 64) * 1024 + hwt * 64;
    for (int kk = grp; kk < 64; kk += 4)
      tile[kk][lane] = src[kk * 1024 + lane];               // coalesced over hw
    __syncthreads();
    for (int rr = grp; rr < 64; rr += 4) {                  // zt: coalesced over k
      const int n = b * 1024 + hwt * 64 + rr;
      zt[n * 256 + kt * 64 + lane] = tile[lane][rr];
    }
    for (int u = t; u < 512; u += 256) {                    // zpk: 16B frag pieces
      const int n_loc = u & 63, kg = u >> 6;
      const int n = b * 1024 + hwt * 64 + n_loc;
      const int k0 = kt * 64 + kg * 8;
      short8 s;
#pragma unroll
      for (int j = 0; j < 8; ++j) s[j] = (short)f2bf(tile[kg * 8 + j][n_loc]);
      *(short8*)(zpk + (size_t)(n >> 4) * 4096 + (k0 >> 5) * 512 +
                 ((k0 >> 3) & 3) * 128 + (n & 15) * 8) = s;
    }
  } else if (bidg < 2048) {                                 // ---- prep_e
    const int u = (bidg - 1024) * 256 + t;                  // 262144 threads
    const int c = u >> 5, k0 = (u & 31) * 8;
    const float4 v0 = *(const float4*)(emb + c * 256 + k0);
    const float4 v1 = *(const float4*)(emb + c * 256 + k0 + 4);
    short8 s;
    s[0] = (short)f2bf(v0.x); s[1] = (short)f2bf(v0.y);
    s[2] = (short)f2bf(v0.z); s[3] = (short)f2bf(v0.w);
    s[4] = (short)f2bf(v1.x); s[5] = (short)f2bf(v1.y);
    s[6] = (short)f2bf(v1.z); s[7] = (short)f2bf(v1.w);
    *(short8*)(epk + (size_t)(c >> 4) * 4096 + (k0 >> 5) * 512 +
               ((k0 >> 3) & 3) * 128 + (c & 15) * 8) = s;
  } else {                                                  // ---- zsum (verbatim)
    const int n = ((bidg - 2048) << 8) + t;
    const int b = n >> 10, hw = n & 1023;
    const float* zb = z + b * 262144 + hw;
    float s = 0.f;
#pragma unroll 8
    for (int c = 0; c < 256; ++c) { const float v = zb[c << 10]; s += v * v; }
    sumz[n] = s;
  }
}

// ---------------- screening GEMM: 64-code (32 KB) panel LDS-resident, barrier-free
// 256 threads / 4 waves; all waves share the 4 code-tiles, wave w owns row-quarter w.
// Block: 1024 rows x 64 codes, 4 strips of 256 rows; per wave-strip 64 rows x 64 codes.
// grid 2048 = 8 XCD x 16 colb x 16 rowg. Fully-unrolled 32-step k-sequence with
// static 3-step-ahead prefetch into zf[32][4]: each fragment loaded once, consumed
// once, ZERO register-rotation v_movs (r13 fix).
__global__ __launch_bounds__(256) void gemm_screen(const ushort* __restrict__ zpk,
                                                   const ushort* __restrict__ epk,
                                                   uint* __restrict__ gmax) {
  __shared__ ushort Cs[16384];   // 32 KB: 32 frags x 1KB, frag f = c16loc*8 + k32
  const int t = threadIdx.x;
  const int w = t >> 6, lane = t & 63;
  const int bid = blockIdx.x;
  const int x = bid & 7, y = bid >> 3;
  const int colb = (y & 15) * 8 + x;       // 0..127; XCD x owns 16 panels (512KB, L2)
  const int rowg = y >> 4;                 // 0..15
  const int n0 = rowg << 10;
  const int m16 = lane & 15, q = lane >> 4;
  // gmax column, XCD-grouped: a 64B line = 4 adjacent (y&15) panels of the SAME x
  // (same XCD) -> concurrent blocks write-combine full lines in their own L2.
  const int cix = x * 64 + (y & 15) * 4 + q;

  // stage code panel once: 8 coalesced 1KB DMAs per wave
#pragma unroll
  for (int f2 = 0; f2 < 8; ++f2) {
    const int f = w * 8 + f2;
    gload_lds16(epk + (size_t)colb * 16384 + f * 512 + lane * 8, (char*)Cs + f * 1024);
  }

  // z fragment address for flattened step v (0..31), row-frag jr:
  //   zw + ((v>>3)*16 + jr)*4096 + (v&7)*512   (elements)
  const ushort* zw = zpk + ((size_t)(n0 >> 4) + w * 4) * 4096 + lane * 8;

  // fully static pipeline: zf[v] loaded at step v-3, consumed at step v.
  short8 zf[32][4];
#pragma unroll
  for (int v = 0; v < 3; ++v)              // prologue primes 3 steps (overlaps DMA)
#pragma unroll
    for (int jr = 0; jr < 4; ++jr)
      zf[v][jr] = *(const short8*)(zw + ((size_t)((v >> 3) * 16 + jr)) * 4096 +
                                   (v & 7) * 512);
  __syncthreads();                         // only barrier in the kernel

#pragma unroll
  for (int strip = 0; strip < 4; ++strip) {
    const int rbase = n0 + strip * 256 + w * 64;
    f32x4 acc[4][4];                       // [ic][jr]
#pragma unroll
    for (int i = 0; i < 4; ++i)
#pragma unroll
      for (int j = 0; j < 4; ++j) acc[i][j] = {0.f, 0.f, 0.f, 0.f};

#pragma unroll
    for (int s32 = 0; s32 < 8; ++s32) {    // k32 steps over K=256 (all static)
      const int v = strip * 8 + s32;
      if (v + 3 < 32) {                    // static condition: prefetch step v+3
        const int u = v + 3;
#pragma unroll
        for (int jr = 0; jr < 4; ++jr)
          zf[u][jr] = *(const short8*)(zw + ((size_t)((u >> 3) * 16 + jr)) * 4096 +
                                       (u & 7) * 512);
      }
      short8 cv[4];
#pragma unroll
      for (int ic = 0; ic < 4; ++ic)
        cv[ic] = *(const short8*)&Cs[(size_t)(ic * 8 + s32) * 512 + lane * 8];
#pragma unroll
      for (int ic = 0; ic < 4; ++ic)
#pragma unroll
        for (int jr = 0; jr < 4; ++jr)
          acc[ic][jr] = __builtin_amdgcn_mfma_f32_16x16x32_bf16(cv[ic], zf[v][jr],
                                                                acc[ic][jr], 0, 0, 0);
    }

    // epilogue: D row=code(q*4+reg), col=z-row(m16). 8-group g0 = q{0,1} regs,
    // g1 = q{2,3}. in-lane reg-max -> xor16 (8-max) -> xor32 (swap halves) -> pack.
#pragma unroll
    for (int jr = 0; jr < 4; ++jr) {
      uint pk[4];
#pragma unroll
      for (int ic = 0; ic < 4; ++ic) {
        float m = fmaxf(fmaxf(acc[ic][jr][0], acc[ic][jr][1]),
                        fmaxf(acc[ic][jr][2], acc[ic][jr][3]));
        m = fmaxf(m, __shfl_xor(m, 16, 64));     // 8-group max (own half)
        const float o = __shfl_xor(m, 32, 64);   // other half's 8-group max
        const float glo = (q & 2) ? o : m;
        const float ghi = (q & 2) ? m : o;
        pk[ic] = (uint)f2bf(glo) | ((uint)f2bf(ghi) << 16);
      }
      const uint sv = (q == 0) ? pk[0] : (q == 1) ? pk[1] : (q == 2) ? pk[2] : pk[3];
      // plain store: completes in L2 (fast vmcnt retirement) and write-combines
      // with same-XCD neighbors (cix layout) -> WRITE_SIZE exactly 32MB (r13)
      gmax[(size_t)(rbase + jr * 16 + m16) * 512 + cix] = sv;
    }
  }
}

// ---------------- wave-per-row: global max over 1024 8-groups -> exact rescore of hits
// Hit compaction is ballot-prefix based: slot order is a pure function of (j, half,
// lane) — bit-identical across replays regardless of wave scheduling (r10 fix).
__global__ __launch_bounds__(256) void select_rescore(const uint* __restrict__ gmax,
                                                      const float* __restrict__ zt,
                                                      const float* __restrict__ emb,
                                                      const float* __restrict__ sumz,
                                                      u64* __restrict__ best) {
  const int t = threadIdx.x, w = t >> 6, lane = t & 63;
  const int n = (blockIdx.x << 2) + w;     // one wave per row, no __syncthreads
  __shared__ float zrow[4][256];
  __shared__ ushort hits[4][128];
  ((float4*)zrow[w])[lane] = ((const float4*)(zt + (size_t)n * 256))[lane];
  const uint4 r0 = ((const uint4*)(gmax + (size_t)n * 512))[lane];        // u32 4l..
  const uint4 r1 = ((const uint4*)(gmax + (size_t)n * 512))[lane + 64];   // 256+4l..
  const uint uv[8] = {r0.x, r0.y, r0.z, r0.w, r1.x, r1.y, r1.z, r1.w};
  float m = -INFINITY;
#pragma unroll
  for (int j = 0; j < 8; ++j) {
    m = fmaxf(m, __uint_as_float(uv[j] << 16));
    m = fmaxf(m, __uint_as_float(uv[j] & 0xffff0000u));
  }
#pragma unroll
  for (int off = 1; off < 64; off <<= 1) m = fmaxf(m, __shfl_xor(m, off, 64));
  const float thr = m - DOT_MARGIN;
  const u64 below = (1ull << lane) - 1ull;
  int base = 0;
#pragma unroll
  for (int j = 0; j < 8; ++j) {
    const int ui = (j < 4) ? lane * 4 + j : 256 + lane * 4 + (j - 4);
    {
      const bool hit = __uint_as_float(uv[j] << 16) >= thr;
      const u64 msk = __ballot(hit);
      if (hit) {
        const int p = base + (int)__popcll(msk & below);
        if (p < 128) hits[w][p] = (ushort)(ui * 2);
      }
      base += (int)__popcll(msk);
    }
    {
      const bool hit = __uint_as_float(uv[j] & 0xffff0000u) >= thr;
      const u64 msk = __ballot(hit);
      if (hit) {
        const int p = base + (int)__popcll(msk & below);
        if (p < 128) hits[w][p] = (ushort)(ui * 2 + 1);
      }
      base += (int)__popcll(msk);
    }
  }
  __threadfence_block();
  int K = base > 128 ? 128 : base;
  const float sz = sumz[n];
  u64 bk = ~0ull;
  for (int id = lane; id < K * 8; id += 64) {
    const int gid = hits[w][id >> 3];
    const int ci = gid >> 1, h = gid & 1;
    // inverse of gemm's XCD-grouped column map: ci = x*64 + yy*4 + q,
    // colb = yy*8 + x, code = colb*64 + q*16 + h*8 + j
    const int c = ((ci >> 2) & 15) * 512 + (ci >> 6) * 64 + (ci & 3) * 16 +
                  h * 8 + (id & 7);
    const float4* ea = (const float4*)(emb + c * 256);
    const float4* za = (const float4*)zrow[w];
    float sdot = 0.f, se = 0.f;
#pragma unroll 8
    for (int k = 0; k < 64; ++k) {          // validated sequential-k fp32 numerics
      const float4 a = za[k], e = ea[k];
      sdot = fmaf(a.x, e.x, sdot); sdot = fmaf(a.y, e.y, sdot);
      sdot = fmaf(a.z, e.z, sdot); sdot = fmaf(a.w, e.w, sdot);
      se = fmaf(e.x, e.x, se); se = fmaf(e.y, e.y, se);
      se = fmaf(e.z, e.z, se); se = fmaf(e.w, e.w, se);
    }
    const float d = (sz + se) - 2.f * sdot;  // matches ref: (sumz+sume) - 2*dot
    const u64 key = ((u64)ford(d) << 32) | (uint)c;
    if (key < bk) bk = key;
  }
#pragma unroll
  for (int off = 1; off < 64; off <<= 1) {
    const u64 o = (((u64)(uint)__shfl_xor((int)(bk >> 32), off, 64)) << 32) |
                  (uint)__shfl_xor((int)(bk & 0xffffffffu), off, 64);
    if (o < bk) bk = o;
  }
  if (lane == 0) best[n] = bk;              // single owner, plain store
}

// ---------------- gather z_q, idx, loss + fused finalize (done-counter)
__global__ __launch_bounds__(256) void gather_kernel(const float* __restrict__ z,
                                                     const float* __restrict__ emb,
                                                     const u64* __restrict__ best,
                                                     float* __restrict__ out,
                                                     double* __restrict__ loss_acc,
                                                     uint* __restrict__ done) {
  const int t = threadIdx.x;
  const int n0 = blockIdx.x << 6;
  const int n = n0 + (t & 63);
  const int idx = (int)(best[n] & 0xffffffffull);
  const int b_i = n >> 10, hw = n & 1023;
  const int c0 = t >> 6;
  const float* zb = z + b_i * 262144 + hw;
  float* ob = out + b_i * 262144 + hw;
  const float* eb = emb + idx * 256;
  float lsum = 0.f;
#pragma unroll 4
  for (int c = c0; c < 256; c += 4) {
    const float ev = eb[c];
    const float zv = zb[c << 10];
    ob[c << 10] = ev;
    const float d = ev - zv;
    lsum += d * d;
  }
  if (c0 == 0) out[4194305 + n] = (float)idx;
#pragma unroll
  for (int off = 32; off; off >>= 1) lsum += __shfl_down(lsum, off, 64);
  __shared__ double wsum[4];
  if ((t & 63) == 0) wsum[t >> 6] = (double)lsum;
  __syncthreads();
  if (t == 0) {
    atomicAdd(loss_acc, wsum[0] + wsum[1] + wsum[2] + wsum[3]);
    __threadfence();
    if (atomicAdd(done, 1u) == 255u) {       // last of 256 blocks
      __threadfence();
      out[4194304] = (float)(1.25 * (*(volatile double*)loss_acc) / 4194304.0);
    }
  }
}

// ---------------- launch
extern "C" void kernel_launch(void* const* d_in, const int* in_sizes, int n_in,
                              void* d_out, int out_size, void* d_ws, size_t ws_size,
                              hipStream_t stream) {
  const float* z = (const float*)d_in[0];
  const float* emb = (const float*)d_in[1];
  float* out = (float*)d_out;
  char* ws = (char*)d_ws;
  float* zt = (float*)(ws + WS_ZT);
  ushort* zpk = (ushort*)(ws + WS_ZPK);
  ushort* epk = (ushort*)(ws + WS_EPK);
  float* sumz = (float*)(ws + WS_SUMZ);
  uint* gmax = (uint*)(ws + WS_GMAX);
  u64* best = (u64*)(ws + WS_BEST);
  double* loss_acc = (double*)(ws + WS_LOSS);
  uint* done = (uint*)(ws + WS_LOSS + 8);

  hipMemsetAsync(ws + WS_LOSS, 0, 16, stream);   // loss_acc + done ctr
  prep_all<<<2112, 256, 0, stream>>>(z, emb, zt, zpk, epk, sumz);
  gemm_screen<<<2048, 256, 0, stream>>>(zpk, epk, gmax);
  select_rescore<<<4096, 256, 0, stream>>>(gmax, zt, emb, sumz, best);
  gather_kernel<<<256, 256, 0, stream>>>(z, emb, best, out, loss_acc, done);
}